// Round 14
// baseline (211.673 us; speedup 1.0000x reference)
//
#include <hip/hip_runtime.h>
#include <hip/hip_bf16.h>
#include <cstdint>

#define THREADS 256

typedef __attribute__((ext_vector_type(8))) short bf16x8;
typedef __attribute__((ext_vector_type(4))) float f32x4;

__device__ __forceinline__ void load_lds16(const void* g, void* l) {
    __builtin_amdgcn_global_load_lds(
        (const __attribute__((address_space(1))) unsigned int*)g,
        (__attribute__((address_space(3))) unsigned int*)l, 16, 0, 0);
}

__device__ __forceinline__ unsigned short f2bf(float x) {
    __hip_bfloat16 hb = __float2bfloat16(x);
    return *(unsigned short*)&hb;
}

// packed RNE pair-convert: lowers to v_cvt_pk_bf16_f32 on gfx950
__device__ __forceinline__ unsigned int f2bf_pk(float a, float b) {
    union { __hip_bfloat162 h2; unsigned int u; } c;
    c.h2 = __float22bfloat162_rn(make_float2(a, b));
    return c.u;
}

// ---------------------------------------------------------------------------
// Fused fp32 -> bf16 cast of the six GEMM inputs. (wk,wv land contiguously)
// ---------------------------------------------------------------------------
__global__ __launch_bounds__(THREADS)
void cast_inputs(const float* __restrict__ xq, const float* __restrict__ xkv,
                 const float* __restrict__ wq, const float* __restrict__ wk,
                 const float* __restrict__ wv, const float* __restrict__ wo,
                 unsigned short* __restrict__ oq, unsigned short* __restrict__ okv,
                 unsigned short* __restrict__ owq, unsigned short* __restrict__ owk,
                 unsigned short* __restrict__ owv, unsigned short* __restrict__ owo) {
    const unsigned n0 = 524288, n1 = 1572864, n2 = 262144, n3 = 196608, n4 = 196608;
    unsigned i = blockIdx.x * THREADS + threadIdx.x;  // < 3014656
    const float* src; unsigned short* dst; unsigned off;
    if (i < n0)                    { src = xq;  dst = oq;  off = i; }
    else if (i < n0+n1)            { src = xkv; dst = okv; off = i - n0; }
    else if (i < n0+n1+n2)         { src = wq;  dst = owq; off = i - n0 - n1; }
    else if (i < n0+n1+n2+n3)      { src = wk;  dst = owk; off = i - n0 - n1 - n2; }
    else if (i < n0+n1+n2+n3+n4)   { src = wv;  dst = owv; off = i - n0 - n1 - n2 - n3; }
    else                           { src = wo;  dst = owo; off = i - n0 - n1 - n2 - n3 - n4; }
    float4 v = *(const float4*)(src + (size_t)off * 4);
    uint2 o;
    o.x = f2bf_pk(v.x, v.y);
    o.y = f2bf_pk(v.z, v.w);
    *(uint2*)(dst + (size_t)off * 4) = o;
}

// ---------------------------------------------------------------------------
// MERGED projection dispatch (grid 1536):
//  blocks [0,1024):   KV GEMM with permuted-KV epilogue (verified r9)
//  blocks [1024,1536): Q GEMM, 64x64 tiles (verified r8/r9 nt64 path)
// ---------------------------------------------------------------------------
__global__ __launch_bounds__(THREADS)
void gemm_proj(const unsigned short* __restrict__ xkv, const unsigned short* __restrict__ wkv,
               unsigned short* __restrict__ Kn, unsigned short* __restrict__ Vt,
               const unsigned short* __restrict__ xq, const unsigned short* __restrict__ wq,
               unsigned short* __restrict__ Qout) {
    __shared__ __align__(16) unsigned short As[128 * 64];
    __shared__ __align__(16) unsigned short Bs[128 * 64];

    const int t    = threadIdx.x;
    const int w    = t >> 6;
    const int lane = t & 63;
    const int l15  = lane & 15;
    const int quad = lane >> 4;
    const int wm   = w & 1;
    const int wn   = w >> 1;

    if (blockIdx.x < 1024) {
        // ---------------- KV path: 128x128 tile, Kd=768 ----------------
        const int bN = (blockIdx.x & 15) * 128;
        const int bM = (blockIdx.x >> 4) * 128;
        const int Kd = 768;

        const int srow = t >> 3;
        const int scol = ((t & 7) ^ ((t >> 4) & 7)) << 3;
        const unsigned short* ga = xkv + (size_t)(bM + srow) * Kd + scol;
        const unsigned short* gb = wkv + (size_t)(bN + srow) * Kd + scol;
        const int lbase = w * 512;

        const int xr = (l15 >> 1) & 7;
        int aoff[2][4], boff[2][4];
#pragma unroll
        for (int kk = 0; kk < 2; ++kk)
#pragma unroll
            for (int mt = 0; mt < 4; ++mt) {
                aoff[kk][mt] = (wm * 64 + mt * 16 + l15) * 64 + (((kk * 4 + quad) ^ xr) << 3);
                boff[kk][mt] = (wn * 64 + mt * 16 + l15) * 64 + (((kk * 4 + quad) ^ xr) << 3);
            }

        f32x4 acc[4][4];
#pragma unroll
        for (int mt = 0; mt < 4; ++mt)
#pragma unroll
            for (int nt = 0; nt < 4; ++nt)
#pragma unroll
                for (int r = 0; r < 4; ++r) acc[mt][nt][r] = 0.f;

        for (int k0 = 0; k0 < Kd; k0 += 64) {
            __syncthreads();
#pragma unroll
            for (int it = 0; it < 4; ++it) {
                load_lds16(ga + (size_t)it * 32 * Kd + k0, &As[lbase + it * 2048]);
                load_lds16(gb + (size_t)it * 32 * Kd + k0, &Bs[lbase + it * 2048]);
            }
            __syncthreads();

#pragma unroll
            for (int kk = 0; kk < 2; ++kk) {
                bf16x8 af[4], bf[4];
#pragma unroll
                for (int mt = 0; mt < 4; ++mt) af[mt] = *(const bf16x8*)&As[aoff[kk][mt]];
#pragma unroll
                for (int nt = 0; nt < 4; ++nt) bf[nt] = *(const bf16x8*)&Bs[boff[kk][nt]];
#pragma unroll
                for (int mt = 0; mt < 4; ++mt)
#pragma unroll
                    for (int nt = 0; nt < 4; ++nt)
                        acc[mt][nt] = __builtin_amdgcn_mfma_f32_16x16x32_bf16(af[mt], bf[nt], acc[mt][nt], 0, 0, 0);
            }
        }

        const int rbase = bM + wm * 64;
        const int b  = rbase >> 12;
        const int h  = (rbase & 4095) >> 8;
        if (bN < 1024) {
            const int G = (bN + wn * 64) >> 6;
            unsigned short* kp = Kn + (size_t)(b * 16 + h) * 262144 + (size_t)G * 256 * 64 + l15;
#pragma unroll
            for (int mt = 0; mt < 4; ++mt)
#pragma unroll
                for (int r = 0; r < 4; ++r) {
                    int u = (rbase & 255) + mt * 16 + quad * 4 + r;
                    unsigned short* cp = kp + (size_t)u * 64;
#pragma unroll
                    for (int nt = 0; nt < 4; ++nt) cp[nt * 16] = f2bf(acc[mt][nt][r]);
                }
        } else {
            const int Gv = (bN - 1024 + wn * 64) >> 6;
            unsigned short* vp = Vt + (size_t)(b * 16 + h) * 262144 + (size_t)Gv * 256;
#pragma unroll
            for (int nt = 0; nt < 4; ++nt) {
                int d = nt * 16 + l15;
#pragma unroll
                for (int mt = 0; mt < 4; ++mt) {
                    int u = (rbase & 255) + mt * 16 + quad * 4;
                    uint2 pk;
                    pk.x = f2bf_pk(acc[mt][nt][0], acc[mt][nt][1]);
                    pk.y = f2bf_pk(acc[mt][nt][2], acc[mt][nt][3]);
                    *(uint2*)(vp + (size_t)d * 4096 + u) = pk;
                }
            }
        }
    } else {
        // ---------------- Q path: 64x64 tile, Kd=1024, N=1024 ----------------
        const int id = blockIdx.x - 1024;           // 0..511
        const int bN = (id & 15) * 64;
        const int bM = (id >> 4) * 64;
        const int Kd = 1024, N = 1024;

        const int srow = t >> 3;                    // 0..31
        const int scol = ((t & 7) ^ ((t >> 3) & 7)) << 3;
        const unsigned short* ga = xq + (size_t)(bM + srow) * Kd + scol;
        const unsigned short* gb = wq + (size_t)(bN + srow) * Kd + scol;
        const int lbase = w * 512;

        int aoff[2][2], boff[2][2];
#pragma unroll
        for (int kk = 0; kk < 2; ++kk)
#pragma unroll
            for (int mt = 0; mt < 2; ++mt) {
                aoff[kk][mt] = (wm * 32 + mt * 16 + l15) * 64 + (((kk * 4 + quad) ^ (l15 & 7)) << 3);
                boff[kk][mt] = (wn * 32 + mt * 16 + l15) * 64 + (((kk * 4 + quad) ^ (l15 & 7)) << 3);
            }

        f32x4 acc[2][2];
#pragma unroll
        for (int mt = 0; mt < 2; ++mt)
#pragma unroll
            for (int nt = 0; nt < 2; ++nt)
#pragma unroll
                for (int r = 0; r < 4; ++r) acc[mt][nt][r] = 0.f;

        for (int k0 = 0; k0 < Kd; k0 += 64) {
            __syncthreads();
#pragma unroll
            for (int it = 0; it < 2; ++it) {
                load_lds16(ga + (size_t)it * 32 * Kd + k0, &As[lbase + it * 2048]);
                load_lds16(gb + (size_t)it * 32 * Kd + k0, &Bs[lbase + it * 2048]);
            }
            __syncthreads();

#pragma unroll
            for (int kk = 0; kk < 2; ++kk) {
                bf16x8 af[2], bf[2];
#pragma unroll
                for (int mt = 0; mt < 2; ++mt) af[mt] = *(const bf16x8*)&As[aoff[kk][mt]];
#pragma unroll
                for (int nt = 0; nt < 2; ++nt) bf[nt] = *(const bf16x8*)&Bs[boff[kk][nt]];
#pragma unroll
                for (int mt = 0; mt < 2; ++mt)
#pragma unroll
                    for (int nt = 0; nt < 2; ++nt)
                        acc[mt][nt] = __builtin_amdgcn_mfma_f32_16x16x32_bf16(af[mt], bf[nt], acc[mt][nt], 0, 0, 0);
            }
        }

#pragma unroll
        for (int mt = 0; mt < 2; ++mt)
#pragma unroll
            for (int r = 0; r < 4; ++r) {
                int row = bM + wm * 32 + mt * 16 + quad * 4 + r;
                int col = bN + wn * 32 + l15;
                unsigned short* cp = Qout + (size_t)row * N + col;
#pragma unroll
                for (int nt = 0; nt < 2; ++nt) cp[nt * 16] = f2bf(acc[mt][nt][r]);
            }
    }
}

// ---------------------------------------------------------------------------
// 64x64-tile bf16 MFMA GEMM (Wo projection). 512 blocks @ 2048x1024.
// ---------------------------------------------------------------------------
template <bool OUTF32>
__global__ __launch_bounds__(THREADS)
void gemm_bf16_nt64(const unsigned short* __restrict__ A, const unsigned short* __restrict__ W,
                    void* __restrict__ Cout, int M, int N, int Kd) {
    __shared__ __align__(16) unsigned short As[64 * 64];
    __shared__ __align__(16) unsigned short Bs[64 * 64];

    const int t    = threadIdx.x;
    const int w    = t >> 6;
    const int lane = t & 63;
    const int l15  = lane & 15;
    const int quad = lane >> 4;
    const int wm   = w & 1;
    const int wn   = w >> 1;
    const int bM = blockIdx.y * 64;
    const int bN = blockIdx.x * 64;

    const int srow = t >> 3;
    const int scol = ((t & 7) ^ ((t >> 3) & 7)) << 3;
    const unsigned short* ga = A + (size_t)(bM + srow) * Kd + scol;
    const unsigned short* gb = W + (size_t)(bN + srow) * Kd + scol;
    const int lbase = w * 512;

    int aoff[2][2], boff[2][2];
#pragma unroll
    for (int kk = 0; kk < 2; ++kk)
#pragma unroll
        for (int mt = 0; mt < 2; ++mt) {
            aoff[kk][mt] = (wm * 32 + mt * 16 + l15) * 64 + (((kk * 4 + quad) ^ (l15 & 7)) << 3);
            boff[kk][mt] = (wn * 32 + mt * 16 + l15) * 64 + (((kk * 4 + quad) ^ (l15 & 7)) << 3);
        }

    f32x4 acc[2][2];
#pragma unroll
    for (int mt = 0; mt < 2; ++mt)
#pragma unroll
        for (int nt = 0; nt < 2; ++nt)
#pragma unroll
            for (int r = 0; r < 4; ++r) acc[mt][nt][r] = 0.f;

    for (int k0 = 0; k0 < Kd; k0 += 64) {
        __syncthreads();
#pragma unroll
        for (int it = 0; it < 2; ++it) {
            load_lds16(ga + (size_t)it * 32 * Kd + k0, &As[lbase + it * 2048]);
            load_lds16(gb + (size_t)it * 32 * Kd + k0, &Bs[lbase + it * 2048]);
        }
        __syncthreads();

#pragma unroll
        for (int kk = 0; kk < 2; ++kk) {
            bf16x8 af[2], bf[2];
#pragma unroll
            for (int mt = 0; mt < 2; ++mt) af[mt] = *(const bf16x8*)&As[aoff[kk][mt]];
#pragma unroll
            for (int nt = 0; nt < 2; ++nt) bf[nt] = *(const bf16x8*)&Bs[boff[kk][nt]];
#pragma unroll
            for (int mt = 0; mt < 2; ++mt)
#pragma unroll
                for (int nt = 0; nt < 2; ++nt)
                    acc[mt][nt] = __builtin_amdgcn_mfma_f32_16x16x32_bf16(af[mt], bf[nt], acc[mt][nt], 0, 0, 0);
        }
    }

#pragma unroll
    for (int mt = 0; mt < 2; ++mt)
#pragma unroll
        for (int r = 0; r < 4; ++r) {
            int row = bM + wm * 32 + mt * 16 + quad * 4 + r;
            int col = bN + wn * 32 + l15;
            if (OUTF32) {
                float* cp = (float*)Cout + (size_t)row * N + col;
#pragma unroll
                for (int nt = 0; nt < 2; ++nt) cp[nt * 16] = acc[mt][nt][r];
            } else {
                unsigned short* cp = (unsigned short*)Cout + (size_t)row * N + col;
#pragma unroll
                for (int nt = 0; nt < 2; ++nt) cp[nt * 16] = f2bf(acc[mt][nt][r]);
            }
        }
}

// ---------------------------------------------------------------------------
// Flash attention v6c: r11 structure; P-store bf16 conversion now via
// packed v_cvt_pk_bf16_f32 (2 instrs for 4 values vs ~12-16 for the scalar
// __float2bfloat16 sequence) — same RNE rounding, bit-identical output.
// ---------------------------------------------------------------------------
__global__ __launch_bounds__(THREADS, 2)
void attn_mfma6(const unsigned short* __restrict__ Q, const unsigned short* __restrict__ K,
                const unsigned short* __restrict__ Vt, unsigned short* __restrict__ AO) {
    extern __shared__ __align__(16) unsigned short sm[];
    unsigned short* Ks = sm;              // [128kv][64d] swizzled, 8192 shorts
    unsigned short* Vs = sm + 8192;       // [64d][128kv] swizzled, 8192 shorts
    unsigned short* Ps = sm + 16384;      // 4 waves x [64q][40], 10240 shorts
    float* OS = (float*)sm;               // epilogue: 3 x [64d][68q] f32
    float* Lw = (float*)(sm + 26624);     // 256 f32

    const int bid  = blockIdx.x;          // 0..511
    const int slot = bid >> 3;
    const int qq   = slot & 15;
    const int hh   = (bid & 7) + 8 * (slot >> 4);
    const int q0 = qq * 64;
    const int h  = hh & 15;
    const int b  = hh >> 4;

    const int t    = threadIdx.x;
    const int w    = t >> 6;              // kv-quarter owner
    const int lane = t & 63;
    const int l15  = lane & 15;
    const int quad = lane >> 4;

    const unsigned short* Qh = Q + (size_t)b * 1048576 + (size_t)h * 65536 + (size_t)q0 * 64;
    const unsigned short* Kh = K + (size_t)b * 4194304 + (size_t)h * 262144;
    const unsigned short* Vh = Vt + (size_t)(b * 16 + h) * 262144;

    bf16x8 Qb[4][2];
#pragma unroll
    for (int qt = 0; qt < 4; ++qt)
#pragma unroll
        for (int kk = 0; kk < 2; ++kk)
            Qb[qt][kk] = *(const bf16x8*)(Qh + (size_t)(qt * 16 + l15) * 64 + kk * 32 + quad * 8);

    const unsigned short* gK = Kh + (size_t)(t >> 3) * 64 + (((t & 7) ^ ((t >> 3) & 7)) << 3);
    const unsigned short* gV = Vh + (size_t)(t >> 4) * 4096 + (((t & 15) ^ ((t >> 4) & 7)) << 3);
    const int lb = w * 512;

    int koff[2][2];
#pragma unroll
    for (int kvt = 0; kvt < 2; ++kvt)
#pragma unroll
        for (int kk = 0; kk < 2; ++kk)
            koff[kvt][kk] = (w * 32 + kvt * 16 + l15) * 64 + (((kk * 4 + quad) ^ (l15 & 7)) << 3);
    int voff[4];
#pragma unroll
    for (int dt = 0; dt < 4; ++dt)
        voff[dt] = (dt * 16 + l15) * 128 + (((w * 4 + quad) ^ (l15 & 7)) << 3);

    const int pw  = w * 2560;
    const int pq  = pw + l15 * 40;

    f32x4 Oacc[4][4];
#pragma unroll
    for (int qt = 0; qt < 4; ++qt)
#pragma unroll
        for (int dt = 0; dt < 4; ++dt)
#pragma unroll
            for (int r = 0; r < 4; ++r) Oacc[qt][dt][r] = 0.f;
    float lsum[4] = {0.f, 0.f, 0.f, 0.f};

    const float scale = 1.0f / 64.0f;

    for (int kc = 0; kc < 32; ++kc) {
        __syncthreads();
#pragma unroll
        for (int it = 0; it < 4; ++it)
            load_lds16(gK + (size_t)kc * 8192 + it * 2048, &Ks[lb + it * 2048]);
#pragma unroll
        for (int it = 0; it < 4; ++it)
            load_lds16(gV + (size_t)kc * 128 + (size_t)it * 65536, &Vs[lb + it * 2048]);
        __syncthreads();

#pragma unroll
        for (int kvt = 0; kvt < 2; ++kvt) {
            bf16x8 ka = *(const bf16x8*)&Ks[koff[kvt][0]];
            bf16x8 kb = *(const bf16x8*)&Ks[koff[kvt][1]];
#pragma unroll
            for (int qt = 0; qt < 4; ++qt) {
                f32x4 S = {0.f, 0.f, 0.f, 0.f};
                S = __builtin_amdgcn_mfma_f32_16x16x32_bf16(ka, Qb[qt][0], S, 0, 0, 0);
                S = __builtin_amdgcn_mfma_f32_16x16x32_bf16(kb, Qb[qt][1], S, 0, 0, 0);
                float p0 = __expf(S[0] * scale);
                float p1 = __expf(S[1] * scale);
                float p2 = __expf(S[2] * scale);
                float p3 = __expf(S[3] * scale);
                lsum[qt] += (p0 + p1) + (p2 + p3);
                uint2 pk;
                pk.x = f2bf_pk(p0, p1);
                pk.y = f2bf_pk(p2, p3);
                *(uint2*)&Ps[pq + qt * 640 + kvt * 16 + quad * 4] = pk;
            }
        }
        asm volatile("s_waitcnt lgkmcnt(0)" ::: "memory");

        bf16x8 Vf[4];
#pragma unroll
        for (int dt = 0; dt < 4; ++dt) Vf[dt] = *(const bf16x8*)&Vs[voff[dt]];
#pragma unroll
        for (int qt = 0; qt < 4; ++qt) {
            bf16x8 Pa = *(const bf16x8*)&Ps[pq + qt * 640 + quad * 8];
#pragma unroll
            for (int dt = 0; dt < 4; ++dt)
                Oacc[qt][dt] = __builtin_amdgcn_mfma_f32_16x16x32_bf16(Pa, Vf[dt], Oacc[qt][dt], 0, 0, 0);
        }
    }

#pragma unroll
    for (int qt = 0; qt < 4; ++qt) {
        float v = lsum[qt];
        v += __shfl_xor(v, 16);
        v += __shfl_xor(v, 32);
        lsum[qt] = v;
    }
    __syncthreads();
    if (lane < 16) {
#pragma unroll
        for (int qt = 0; qt < 4; ++qt)
            Lw[w * 64 + qt * 16 + lane] = lsum[qt];
    }
    if (w > 0) {
        float* myOS = OS + (w - 1) * 4352;
#pragma unroll
        for (int qt = 0; qt < 4; ++qt)
#pragma unroll
            for (int dt = 0; dt < 4; ++dt)
                *(f32x4*)&myOS[(dt * 16 + l15) * 68 + qt * 16 + quad * 4] = Oacc[qt][dt];
    }
    __syncthreads();
    if (w == 0) {
#pragma unroll
        for (int qt = 0; qt < 4; ++qt) {
            f32x4 lv = *(const f32x4*)&Lw[qt * 16 + quad * 4];
            lv += *(const f32x4*)&Lw[64 + qt * 16 + quad * 4];
            lv += *(const f32x4*)&Lw[128 + qt * 16 + quad * 4];
            lv += *(const f32x4*)&Lw[192 + qt * 16 + quad * 4];
            f32x4 inv;
#pragma unroll
            for (int r = 0; r < 4; ++r) inv[r] = 1.0f / lv[r];
#pragma unroll
            for (int dt = 0; dt < 4; ++dt) {
                f32x4 o = Oacc[qt][dt];
                int os = (dt * 16 + l15) * 68 + qt * 16 + quad * 4;
                o += *(const f32x4*)&OS[os];
                o += *(const f32x4*)&OS[4352 + os];
                o += *(const f32x4*)&OS[8704 + os];
                unsigned int c01 = f2bf_pk(o[0] * inv[0], o[1] * inv[1]);
                unsigned int c23 = f2bf_pk(o[2] * inv[2], o[3] * inv[3]);
                unsigned short s01[2], s23[2];
                *(unsigned int*)s01 = c01;
                *(unsigned int*)s23 = c23;
#pragma unroll
                for (int r = 0; r < 4; ++r) {
                    int q = qt * 16 + quad * 4 + r;
                    AO[(size_t)b * 1048576 + (size_t)(q0 + q) * 1024 + (h << 6) + dt * 16 + l15]
                        = (r < 2) ? s01[r] : s23[r - 2];
                }
            }
        }
    }
}

// ---------------------------------------------------------------------------
extern "C" void kernel_launch(void* const* d_in, const int* in_sizes, int n_in,
                              void* d_out, int out_size, void* d_ws, size_t ws_size,
                              hipStream_t stream) {
    const float* x_q  = (const float*)d_in[0];  // (2,1024,1024)
    const float* x_kv = (const float*)d_in[1];  // (2,4096,768)
    const float* Wq   = (const float*)d_in[2];
    const float* Wk   = (const float*)d_in[3];
    const float* Wv   = (const float*)d_in[4];
    const float* Wo   = (const float*)d_in[5];
    float* out = (float*)d_out;

    unsigned short* base   = (unsigned short*)d_ws;
    unsigned short* xq_bf  = base;                  // 2097152
    unsigned short* xkv_bf = base + 2097152;        // 6291456
    unsigned short* wq_bf  = base + 8388608;        // 1048576
    unsigned short* wk_bf  = base + 9437184;        //  786432  \ contiguous
    unsigned short* wv_bf  = base + 10223616;       //  786432  / [2048][768]
    unsigned short* wo_bf  = base + 11010048;       // 1048576
    unsigned short* Qw     = base + 12058624;       // 2097152
    unsigned short* Kw     = base + 14155776;       // 8388608
    unsigned short* AOb    = base + 22544384;       // 2097152
    unsigned short* Vtw    = base + 30932992;       // 8388608

    dim3 blk(THREADS);
    cast_inputs<<<dim3(11776), blk, 0, stream>>>(x_q, x_kv, Wq, Wk, Wv, Wo,
                                                 xq_bf, xkv_bf, wq_bf, wk_bf, wv_bf, wo_bf);
    gemm_proj<<<dim3(1536), blk, 0, stream>>>(xkv_bf, wk_bf, Kw, Vtw, xq_bf, wq_bf, Qw);
    attn_mfma6<<<dim3(512), blk, 54272, stream>>>(Qw, Kw, Vtw, AOb);
    gemm_bf16_nt64<true><<<dim3(16, 32), blk, 0, stream>>>(AOb, wo_bf, (void*)out, 2048, 1024, 1024);
}

// Round 15
// 205.208 us; speedup vs baseline: 1.0315x; 1.0315x over previous
//
#include <hip/hip_runtime.h>
#include <hip/hip_bf16.h>
#include <cstdint>

#define THREADS 256

typedef __attribute__((ext_vector_type(8))) short bf16x8;
typedef __attribute__((ext_vector_type(4))) float f32x4;

__device__ __forceinline__ void load_lds16(const void* g, void* l) {
    __builtin_amdgcn_global_load_lds(
        (const __attribute__((address_space(1))) unsigned int*)g,
        (__attribute__((address_space(3))) unsigned int*)l, 16, 0, 0);
}

__device__ __forceinline__ unsigned short f2bf(float x) {
    __hip_bfloat16 hb = __float2bfloat16(x);
    return *(unsigned short*)&hb;
}

// ---------------------------------------------------------------------------
// Fused fp32 -> bf16 cast of the six GEMM inputs. (r13 verbatim)
// ---------------------------------------------------------------------------
__global__ __launch_bounds__(THREADS)
void cast_inputs(const float* __restrict__ xq, const float* __restrict__ xkv,
                 const float* __restrict__ wq, const float* __restrict__ wk,
                 const float* __restrict__ wv, const float* __restrict__ wo,
                 unsigned short* __restrict__ oq, unsigned short* __restrict__ okv,
                 unsigned short* __restrict__ owq, unsigned short* __restrict__ owk,
                 unsigned short* __restrict__ owv, unsigned short* __restrict__ owo) {
    const unsigned n0 = 524288, n1 = 1572864, n2 = 262144, n3 = 196608, n4 = 196608;
    unsigned i = blockIdx.x * THREADS + threadIdx.x;  // < 3014656
    const float* src; unsigned short* dst; unsigned off;
    if (i < n0)                    { src = xq;  dst = oq;  off = i; }
    else if (i < n0+n1)            { src = xkv; dst = okv; off = i - n0; }
    else if (i < n0+n1+n2)         { src = wq;  dst = owq; off = i - n0 - n1; }
    else if (i < n0+n1+n2+n3)      { src = wk;  dst = owk; off = i - n0 - n1 - n2; }
    else if (i < n0+n1+n2+n3+n4)   { src = wv;  dst = owv; off = i - n0 - n1 - n2 - n3; }
    else                           { src = wo;  dst = owo; off = i - n0 - n1 - n2 - n3 - n4; }
    float4 v = *(const float4*)(src + (size_t)off * 4);
    ushort4 o;
    o.x = f2bf(v.x); o.y = f2bf(v.y); o.z = f2bf(v.z); o.w = f2bf(v.w);
    *(ushort4*)(dst + (size_t)off * 4) = o;
}

// ---------------------------------------------------------------------------
// MERGED projection dispatch (grid 1536). (r13 verbatim)
// ---------------------------------------------------------------------------
__global__ __launch_bounds__(THREADS)
void gemm_proj(const unsigned short* __restrict__ xkv, const unsigned short* __restrict__ wkv,
               unsigned short* __restrict__ Kn, unsigned short* __restrict__ Vt,
               const unsigned short* __restrict__ xq, const unsigned short* __restrict__ wq,
               unsigned short* __restrict__ Qout) {
    __shared__ __align__(16) unsigned short As[128 * 64];
    __shared__ __align__(16) unsigned short Bs[128 * 64];

    const int t    = threadIdx.x;
    const int w    = t >> 6;
    const int lane = t & 63;
    const int l15  = lane & 15;
    const int quad = lane >> 4;
    const int wm   = w & 1;
    const int wn   = w >> 1;

    if (blockIdx.x < 1024) {
        const int bN = (blockIdx.x & 15) * 128;
        const int bM = (blockIdx.x >> 4) * 128;
        const int Kd = 768;

        const int srow = t >> 3;
        const int scol = ((t & 7) ^ ((t >> 4) & 7)) << 3;
        const unsigned short* ga = xkv + (size_t)(bM + srow) * Kd + scol;
        const unsigned short* gb = wkv + (size_t)(bN + srow) * Kd + scol;
        const int lbase = w * 512;

        const int xr = (l15 >> 1) & 7;
        int aoff[2][4], boff[2][4];
#pragma unroll
        for (int kk = 0; kk < 2; ++kk)
#pragma unroll
            for (int mt = 0; mt < 4; ++mt) {
                aoff[kk][mt] = (wm * 64 + mt * 16 + l15) * 64 + (((kk * 4 + quad) ^ xr) << 3);
                boff[kk][mt] = (wn * 64 + mt * 16 + l15) * 64 + (((kk * 4 + quad) ^ xr) << 3);
            }

        f32x4 acc[4][4];
#pragma unroll
        for (int mt = 0; mt < 4; ++mt)
#pragma unroll
            for (int nt = 0; nt < 4; ++nt)
#pragma unroll
                for (int r = 0; r < 4; ++r) acc[mt][nt][r] = 0.f;

        for (int k0 = 0; k0 < Kd; k0 += 64) {
            __syncthreads();
#pragma unroll
            for (int it = 0; it < 4; ++it) {
                load_lds16(ga + (size_t)it * 32 * Kd + k0, &As[lbase + it * 2048]);
                load_lds16(gb + (size_t)it * 32 * Kd + k0, &Bs[lbase + it * 2048]);
            }
            __syncthreads();

#pragma unroll
            for (int kk = 0; kk < 2; ++kk) {
                bf16x8 af[4], bf[4];
#pragma unroll
                for (int mt = 0; mt < 4; ++mt) af[mt] = *(const bf16x8*)&As[aoff[kk][mt]];
#pragma unroll
                for (int nt = 0; nt < 4; ++nt) bf[nt] = *(const bf16x8*)&Bs[boff[kk][nt]];
#pragma unroll
                for (int mt = 0; mt < 4; ++mt)
#pragma unroll
                    for (int nt = 0; nt < 4; ++nt)
                        acc[mt][nt] = __builtin_amdgcn_mfma_f32_16x16x32_bf16(af[mt], bf[nt], acc[mt][nt], 0, 0, 0);
            }
        }

        const int rbase = bM + wm * 64;
        const int b  = rbase >> 12;
        const int h  = (rbase & 4095) >> 8;
        if (bN < 1024) {
            const int G = (bN + wn * 64) >> 6;
            unsigned short* kp = Kn + (size_t)(b * 16 + h) * 262144 + (size_t)G * 256 * 64 + l15;
#pragma unroll
            for (int mt = 0; mt < 4; ++mt)
#pragma unroll
                for (int r = 0; r < 4; ++r) {
                    int u = (rbase & 255) + mt * 16 + quad * 4 + r;
                    unsigned short* cp = kp + (size_t)u * 64;
#pragma unroll
                    for (int nt = 0; nt < 4; ++nt) cp[nt * 16] = f2bf(acc[mt][nt][r]);
                }
        } else {
            const int Gv = (bN - 1024 + wn * 64) >> 6;
            unsigned short* vp = Vt + (size_t)(b * 16 + h) * 262144 + (size_t)Gv * 256;
#pragma unroll
            for (int nt = 0; nt < 4; ++nt) {
                int d = nt * 16 + l15;
#pragma unroll
                for (int mt = 0; mt < 4; ++mt) {
                    int u = (rbase & 255) + mt * 16 + quad * 4;
                    ushort4 pk;
                    pk.x = f2bf(acc[mt][nt][0]);
                    pk.y = f2bf(acc[mt][nt][1]);
                    pk.z = f2bf(acc[mt][nt][2]);
                    pk.w = f2bf(acc[mt][nt][3]);
                    *(ushort4*)(vp + (size_t)d * 4096 + u) = pk;
                }
            }
        }
    } else {
        const int id = blockIdx.x - 1024;           // 0..511
        const int bN = (id & 15) * 64;
        const int bM = (id >> 4) * 64;
        const int Kd = 1024, N = 1024;

        const int srow = t >> 3;
        const int scol = ((t & 7) ^ ((t >> 3) & 7)) << 3;
        const unsigned short* ga = xq + (size_t)(bM + srow) * Kd + scol;
        const unsigned short* gb = wq + (size_t)(bN + srow) * Kd + scol;
        const int lbase = w * 512;

        int aoff[2][2], boff[2][2];
#pragma unroll
        for (int kk = 0; kk < 2; ++kk)
#pragma unroll
            for (int mt = 0; mt < 2; ++mt) {
                aoff[kk][mt] = (wm * 32 + mt * 16 + l15) * 64 + (((kk * 4 + quad) ^ (l15 & 7)) << 3);
                boff[kk][mt] = (wn * 32 + mt * 16 + l15) * 64 + (((kk * 4 + quad) ^ (l15 & 7)) << 3);
            }

        f32x4 acc[2][2];
#pragma unroll
        for (int mt = 0; mt < 2; ++mt)
#pragma unroll
            for (int nt = 0; nt < 2; ++nt)
#pragma unroll
                for (int r = 0; r < 4; ++r) acc[mt][nt][r] = 0.f;

        for (int k0 = 0; k0 < Kd; k0 += 64) {
            __syncthreads();
#pragma unroll
            for (int it = 0; it < 2; ++it) {
                load_lds16(ga + (size_t)it * 32 * Kd + k0, &As[lbase + it * 2048]);
                load_lds16(gb + (size_t)it * 32 * Kd + k0, &Bs[lbase + it * 2048]);
            }
            __syncthreads();

#pragma unroll
            for (int kk = 0; kk < 2; ++kk) {
                bf16x8 af[2], bf[2];
#pragma unroll
                for (int mt = 0; mt < 2; ++mt) af[mt] = *(const bf16x8*)&As[aoff[kk][mt]];
#pragma unroll
                for (int nt = 0; nt < 2; ++nt) bf[nt] = *(const bf16x8*)&Bs[boff[kk][nt]];
#pragma unroll
                for (int mt = 0; mt < 2; ++mt)
#pragma unroll
                    for (int nt = 0; nt < 2; ++nt)
                        acc[mt][nt] = __builtin_amdgcn_mfma_f32_16x16x32_bf16(af[mt], bf[nt], acc[mt][nt], 0, 0, 0);
            }
        }

#pragma unroll
        for (int mt = 0; mt < 2; ++mt)
#pragma unroll
            for (int r = 0; r < 4; ++r) {
                int row = bM + wm * 32 + mt * 16 + quad * 4 + r;
                int col = bN + wn * 32 + l15;
                unsigned short* cp = Qout + (size_t)row * N + col;
#pragma unroll
                for (int nt = 0; nt < 2; ++nt) cp[nt * 16] = f2bf(acc[mt][nt][r]);
            }
    }
}

// ---------------------------------------------------------------------------
// 64x64-tile bf16 MFMA GEMM (Wo projection). (r13 verbatim)
// ---------------------------------------------------------------------------
template <bool OUTF32>
__global__ __launch_bounds__(THREADS)
void gemm_bf16_nt64(const unsigned short* __restrict__ A, const unsigned short* __restrict__ W,
                    void* __restrict__ Cout, int M, int N, int Kd) {
    __shared__ __align__(16) unsigned short As[64 * 64];
    __shared__ __align__(16) unsigned short Bs[64 * 64];

    const int t    = threadIdx.x;
    const int w    = t >> 6;
    const int lane = t & 63;
    const int l15  = lane & 15;
    const int quad = lane >> 4;
    const int wm   = w & 1;
    const int wn   = w >> 1;
    const int bM = blockIdx.y * 64;
    const int bN = blockIdx.x * 64;

    const int srow = t >> 3;
    const int scol = ((t & 7) ^ ((t >> 3) & 7)) << 3;
    const unsigned short* ga = A + (size_t)(bM + srow) * Kd + scol;
    const unsigned short* gb = W + (size_t)(bN + srow) * Kd + scol;
    const int lbase = w * 512;

    int aoff[2][2], boff[2][2];
#pragma unroll
    for (int kk = 0; kk < 2; ++kk)
#pragma unroll
        for (int mt = 0; mt < 2; ++mt) {
            aoff[kk][mt] = (wm * 32 + mt * 16 + l15) * 64 + (((kk * 4 + quad) ^ (l15 & 7)) << 3);
            boff[kk][mt] = (wn * 32 + mt * 16 + l15) * 64 + (((kk * 4 + quad) ^ (l15 & 7)) << 3);
        }

    f32x4 acc[2][2];
#pragma unroll
    for (int mt = 0; mt < 2; ++mt)
#pragma unroll
        for (int nt = 0; nt < 2; ++nt)
#pragma unroll
            for (int r = 0; r < 4; ++r) acc[mt][nt][r] = 0.f;

    for (int k0 = 0; k0 < Kd; k0 += 64) {
        __syncthreads();
#pragma unroll
        for (int it = 0; it < 2; ++it) {
            load_lds16(ga + (size_t)it * 32 * Kd + k0, &As[lbase + it * 2048]);
            load_lds16(gb + (size_t)it * 32 * Kd + k0, &Bs[lbase + it * 2048]);
        }
        __syncthreads();

#pragma unroll
        for (int kk = 0; kk < 2; ++kk) {
            bf16x8 af[2], bf[2];
#pragma unroll
            for (int mt = 0; mt < 2; ++mt) af[mt] = *(const bf16x8*)&As[aoff[kk][mt]];
#pragma unroll
            for (int nt = 0; nt < 2; ++nt) bf[nt] = *(const bf16x8*)&Bs[boff[kk][nt]];
#pragma unroll
            for (int mt = 0; mt < 2; ++mt)
#pragma unroll
                for (int nt = 0; nt < 2; ++nt)
                    acc[mt][nt] = __builtin_amdgcn_mfma_f32_16x16x32_bf16(af[mt], bf[nt], acc[mt][nt], 0, 0, 0);
        }
    }

#pragma unroll
    for (int mt = 0; mt < 2; ++mt)
#pragma unroll
        for (int r = 0; r < 4; ++r) {
            int row = bM + wm * 32 + mt * 16 + quad * 4 + r;
            int col = bN + wn * 32 + l15;
            if (OUTF32) {
                float* cp = (float*)Cout + (size_t)row * N + col;
#pragma unroll
                for (int nt = 0; nt < 2; ++nt) cp[nt * 16] = acc[mt][nt][r];
            } else {
                unsigned short* cp = (unsigned short*)Cout + (size_t)row * N + col;
#pragma unroll
                for (int nt = 0; nt < 2; ++nt) cp[nt * 16] = f2bf(acc[mt][nt][r]);
            }
        }
}

// ---------------------------------------------------------------------------
// Flash attention v8: BARRIER-FREE K-loop.
// Insight: in the r11 tiling (64q x 32kv per wave, S^T trick) no wave reads
// another wave's staged data: wave w consumes K rows [32w,32w+32), V columns
// [32w,32w+32), private P. So each wave stages exactly its own slice and the
// block-wide __syncthreads pair (the m97-style vmcnt(0)+barrier drain, ~10 µs
// of serialization) disappears — per-wave s_waitcnt vmcnt(0) only.
//  - Ks: same [128][64] row-swizzled layout, rows [32w,+32) staged by wave w
//    (base rows ≡0 mod 8 keep the swizzle formula; frag reads unchanged).
//  - Vs2: quarter-major [w][64d][4 granules], granule swizzle g^=(d&3);
//    lane-consecutive 16B -> global_load_lds expressible; B-frag reads keep
//    the verified layout (n=d=l15, k=quad*8+j), worst 4-way bank conflict.
//  - Hazard ordering: the per-iter asm fences (vmcnt0 after loads, lgkmcnt0
//    after P stores) order all LDS WAR windows; loads touch only Ks/Vs.
//  - Epilogue unchanged (has its own __syncthreads before the OS overlay).
// ---------------------------------------------------------------------------
__global__ __launch_bounds__(THREADS, 2)
void attn_mfma8(const unsigned short* __restrict__ Q, const unsigned short* __restrict__ K,
                const unsigned short* __restrict__ Vt, unsigned short* __restrict__ AO) {
    extern __shared__ __align__(16) unsigned short sm[];
    unsigned short* Ks = sm;              // [128kv][64d] row-swizzled, 8192 shorts
    unsigned short* Vs = sm + 8192;       // quarter-major [w][64d][4x16B], 8192 shorts
    unsigned short* Ps = sm + 16384;      // 4 waves x [64q][40], 10240 shorts
    float* OS = (float*)sm;               // epilogue: 3 x [64d][68q] f32
    float* Lw = (float*)(sm + 26624);     // 256 f32

    const int bid  = blockIdx.x;          // 0..511
    const int slot = bid >> 3;
    const int qq   = slot & 15;
    const int hh   = (bid & 7) + 8 * (slot >> 4);
    const int q0 = qq * 64;
    const int h  = hh & 15;
    const int b  = hh >> 4;

    const int t    = threadIdx.x;
    const int w    = t >> 6;              // kv-quarter owner
    const int lane = t & 63;
    const int l15  = lane & 15;
    const int quad = lane >> 4;

    const unsigned short* Qh = Q + (size_t)b * 1048576 + (size_t)h * 65536 + (size_t)q0 * 64;
    const unsigned short* Kh = K + (size_t)b * 4194304 + (size_t)h * 262144;
    const unsigned short* Vh = Vt + (size_t)(b * 16 + h) * 262144;

    bf16x8 Qb[4][2];
#pragma unroll
    for (int qt = 0; qt < 4; ++qt)
#pragma unroll
        for (int kk = 0; kk < 2; ++kk)
            Qb[qt][kk] = *(const bf16x8*)(Qh + (size_t)(qt * 16 + l15) * 64 + kk * 32 + quad * 8);

    // wave-private staging pointers
    //  K: lane covers row 32w + it*8 + (lane>>3), granule (lane&7)^((lane>>3)&7)
    const unsigned short* gKw = Kh + (size_t)(w * 32 + (lane >> 3)) * 64
                                   + (((lane & 7) ^ ((lane >> 3) & 7)) << 3);
    //  V: lane covers d = it*16 + (lane>>2), quarter-col granule (lane&3)^((lane>>2)&3)
    const unsigned short* gVw = Vh + (size_t)(lane >> 2) * 4096 + w * 32
                                   + (((lane & 3) ^ ((lane >> 2) & 3)) << 3);
    const int ldsK = w * 2048;            // + it*512 (shorts)
    const int ldsV = w * 2048;            // + it*512 (shorts), within Vs

    // frag-read offsets
    int koff[2][2];
#pragma unroll
    for (int kvt = 0; kvt < 2; ++kvt)
#pragma unroll
        for (int kk = 0; kk < 2; ++kk)
            koff[kvt][kk] = (w * 32 + kvt * 16 + l15) * 64 + (((kk * 4 + quad) ^ (l15 & 7)) << 3);
    int voff[4];
#pragma unroll
    for (int dt = 0; dt < 4; ++dt)
        voff[dt] = w * 2048 + (dt * 16 + l15) * 32 + ((quad ^ (l15 & 3)) << 3);

    const int pw  = w * 2560;
    const int pq  = pw + l15 * 40;

    f32x4 Oacc[4][4];
#pragma unroll
    for (int qt = 0; qt < 4; ++qt)
#pragma unroll
        for (int dt = 0; dt < 4; ++dt)
#pragma unroll
            for (int r = 0; r < 4; ++r) Oacc[qt][dt][r] = 0.f;
    float lsum[4] = {0.f, 0.f, 0.f, 0.f};

    const float scale = 1.0f / 64.0f;

    for (int kc = 0; kc < 32; ++kc) {
        // ---- wave-private staging: no block barrier ----
#pragma unroll
        for (int it = 0; it < 4; ++it)
            load_lds16(gKw + (size_t)kc * 8192 + it * 512, &Ks[ldsK + it * 512]);
#pragma unroll
        for (int it = 0; it < 4; ++it)
            load_lds16(gVw + (size_t)kc * 128 + (size_t)it * 65536, &Vs[ldsV + it * 512]);
        asm volatile("s_waitcnt vmcnt(0)" ::: "memory");   // this wave's tiles ready

        // ---- S^T tiles (16kv x 16q), __expf, b64 P store ----
#pragma unroll
        for (int kvt = 0; kvt < 2; ++kvt) {
            bf16x8 ka = *(const bf16x8*)&Ks[koff[kvt][0]];
            bf16x8 kb = *(const bf16x8*)&Ks[koff[kvt][1]];
#pragma unroll
            for (int qt = 0; qt < 4; ++qt) {
                f32x4 S = {0.f, 0.f, 0.f, 0.f};
                S = __builtin_amdgcn_mfma_f32_16x16x32_bf16(ka, Qb[qt][0], S, 0, 0, 0);
                S = __builtin_amdgcn_mfma_f32_16x16x32_bf16(kb, Qb[qt][1], S, 0, 0, 0);
                float p0 = __expf(S[0] * scale);
                float p1 = __expf(S[1] * scale);
                float p2 = __expf(S[2] * scale);
                float p3 = __expf(S[3] * scale);
                lsum[qt] += (p0 + p1) + (p2 + p3);
                ushort4 pk4;
                pk4.x = f2bf(p0); pk4.y = f2bf(p1); pk4.z = f2bf(p2); pk4.w = f2bf(p3);
                *(ushort4*)&Ps[pq + qt * 640 + kvt * 16 + quad * 4] = pk4;
            }
        }

        // V-frag reads are independent of the P stores: issue before the drain
        bf16x8 Vf[4];
#pragma unroll
        for (int dt = 0; dt < 4; ++dt) Vf[dt] = *(const bf16x8*)&Vs[voff[dt]];
        asm volatile("s_waitcnt lgkmcnt(0)" ::: "memory");  // P (and Vf) visible

        // ---- O += P @ V over this wave's 32 kv ----
#pragma unroll
        for (int qt = 0; qt < 4; ++qt) {
            bf16x8 Pa = *(const bf16x8*)&Ps[pq + qt * 640 + quad * 8];
#pragma unroll
            for (int dt = 0; dt < 4; ++dt)
                Oacc[qt][dt] = __builtin_amdgcn_mfma_f32_16x16x32_bf16(Pa, Vf[dt], Oacc[qt][dt], 0, 0, 0);
        }
    }

    // ---- epilogue (unchanged from r11/r13) ----
#pragma unroll
    for (int qt = 0; qt < 4; ++qt) {
        float v = lsum[qt];
        v += __shfl_xor(v, 16);
        v += __shfl_xor(v, 32);
        lsum[qt] = v;
    }
    __syncthreads();   // (1) all waves done with Ks/Vs/Ps
    if (lane < 16) {
#pragma unroll
        for (int qt = 0; qt < 4; ++qt)
            Lw[w * 64 + qt * 16 + lane] = lsum[qt];
    }
    if (w > 0) {
        float* myOS = OS + (w - 1) * 4352;
#pragma unroll
        for (int qt = 0; qt < 4; ++qt)
#pragma unroll
            for (int dt = 0; dt < 4; ++dt)
                *(f32x4*)&myOS[(dt * 16 + l15) * 68 + qt * 16 + quad * 4] = Oacc[qt][dt];
    }
    __syncthreads();   // (2) partials + Lw visible
    if (w == 0) {
#pragma unroll
        for (int qt = 0; qt < 4; ++qt) {
            f32x4 lv = *(const f32x4*)&Lw[qt * 16 + quad * 4];
            lv += *(const f32x4*)&Lw[64 + qt * 16 + quad * 4];
            lv += *(const f32x4*)&Lw[128 + qt * 16 + quad * 4];
            lv += *(const f32x4*)&Lw[192 + qt * 16 + quad * 4];
            f32x4 inv;
#pragma unroll
            for (int r = 0; r < 4; ++r) inv[r] = 1.0f / lv[r];
#pragma unroll
            for (int dt = 0; dt < 4; ++dt) {
                f32x4 o = Oacc[qt][dt];
                int os = (dt * 16 + l15) * 68 + qt * 16 + quad * 4;
                o += *(const f32x4*)&OS[os];
                o += *(const f32x4*)&OS[4352 + os];
                o += *(const f32x4*)&OS[8704 + os];
#pragma unroll
                for (int r = 0; r < 4; ++r) {
                    int q = qt * 16 + quad * 4 + r;
                    AO[(size_t)b * 1048576 + (size_t)(q0 + q) * 1024 + (h << 6) + dt * 16 + l15]
                        = f2bf(o[r] * inv[r]);
                }
            }
        }
    }
}

// ---------------------------------------------------------------------------
extern "C" void kernel_launch(void* const* d_in, const int* in_sizes, int n_in,
                              void* d_out, int out_size, void* d_ws, size_t ws_size,
                              hipStream_t stream) {
    const float* x_q  = (const float*)d_in[0];  // (2,1024,1024)
    const float* x_kv = (const float*)d_in[1];  // (2,4096,768)
    const float* Wq   = (const float*)d_in[2];
    const float* Wk   = (const float*)d_in[3];
    const float* Wv   = (const float*)d_in[4];
    const float* Wo   = (const float*)d_in[5];
    float* out = (float*)d_out;

    unsigned short* base   = (unsigned short*)d_ws;
    unsigned short* xq_bf  = base;                  // 2097152
    unsigned short* xkv_bf = base + 2097152;        // 6291456
    unsigned short* wq_bf  = base + 8388608;        // 1048576
    unsigned short* wk_bf  = base + 9437184;        //  786432  \ contiguous
    unsigned short* wv_bf  = base + 10223616;       //  786432  / [2048][768]
    unsigned short* wo_bf  = base + 11010048;       // 1048576
    unsigned short* Qw     = base + 12058624;       // 2097152
    unsigned short* Kw     = base + 14155776;       // 8388608
    unsigned short* AOb    = base + 22544384;       // 2097152
    unsigned short* Vtw    = base + 30932992;       // 8388608

    dim3 blk(THREADS);
    cast_inputs<<<dim3(11776), blk, 0, stream>>>(x_q, x_kv, Wq, Wk, Wv, Wo,
                                                 xq_bf, xkv_bf, wq_bf, wk_bf, wv_bf, wo_bf);
    gemm_proj<<<dim3(1536), blk, 0, stream>>>(xkv_bf, wk_bf, Kw, Vtw, xq_bf, wq_bf, Qw);
    attn_mfma8<<<dim3(512), blk, 54272, stream>>>(Qw, Kw, Vtw, AOb);
    gemm_bf16_nt64<true><<<dim3(16, 32), blk, 0, stream>>>(AOb, wo_bf, (void*)out, 2048, 1024, 1024);
}

// Round 16
// 201.226 us; speedup vs baseline: 1.0519x; 1.0198x over previous
//
#include <hip/hip_runtime.h>
#include <hip/hip_bf16.h>
#include <cstdint>

#define THREADS 256

typedef __attribute__((ext_vector_type(8))) short bf16x8;
typedef __attribute__((ext_vector_type(4))) float f32x4;

__device__ __forceinline__ void load_lds16(const void* g, void* l) {
    __builtin_amdgcn_global_load_lds(
        (const __attribute__((address_space(1))) unsigned int*)g,
        (__attribute__((address_space(3))) unsigned int*)l, 16, 0, 0);
}

__device__ __forceinline__ unsigned short f2bf(float x) {
    __hip_bfloat16 hb = __float2bfloat16(x);
    return *(unsigned short*)&hb;
}

// ---------------------------------------------------------------------------
// Fused fp32 -> bf16 cast of the six GEMM inputs. (r13 verbatim)
// ---------------------------------------------------------------------------
__global__ __launch_bounds__(THREADS)
void cast_inputs(const float* __restrict__ xq, const float* __restrict__ xkv,
                 const float* __restrict__ wq, const float* __restrict__ wk,
                 const float* __restrict__ wv, const float* __restrict__ wo,
                 unsigned short* __restrict__ oq, unsigned short* __restrict__ okv,
                 unsigned short* __restrict__ owq, unsigned short* __restrict__ owk,
                 unsigned short* __restrict__ owv, unsigned short* __restrict__ owo) {
    const unsigned n0 = 524288, n1 = 1572864, n2 = 262144, n3 = 196608, n4 = 196608;
    unsigned i = blockIdx.x * THREADS + threadIdx.x;  // < 3014656
    const float* src; unsigned short* dst; unsigned off;
    if (i < n0)                    { src = xq;  dst = oq;  off = i; }
    else if (i < n0+n1)            { src = xkv; dst = okv; off = i - n0; }
    else if (i < n0+n1+n2)         { src = wq;  dst = owq; off = i - n0 - n1; }
    else if (i < n0+n1+n2+n3)      { src = wk;  dst = owk; off = i - n0 - n1 - n2; }
    else if (i < n0+n1+n2+n3+n4)   { src = wv;  dst = owv; off = i - n0 - n1 - n2 - n3; }
    else                           { src = wo;  dst = owo; off = i - n0 - n1 - n2 - n3 - n4; }
    float4 v = *(const float4*)(src + (size_t)off * 4);
    ushort4 o;
    o.x = f2bf(v.x); o.y = f2bf(v.y); o.z = f2bf(v.z); o.w = f2bf(v.w);
    *(ushort4*)(dst + (size_t)off * 4) = o;
}

// ---------------------------------------------------------------------------
// MERGED projection dispatch (grid 1536). (r13 verbatim)
// ---------------------------------------------------------------------------
__global__ __launch_bounds__(THREADS)
void gemm_proj(const unsigned short* __restrict__ xkv, const unsigned short* __restrict__ wkv,
               unsigned short* __restrict__ Kn, unsigned short* __restrict__ Vt,
               const unsigned short* __restrict__ xq, const unsigned short* __restrict__ wq,
               unsigned short* __restrict__ Qout) {
    __shared__ __align__(16) unsigned short As[128 * 64];
    __shared__ __align__(16) unsigned short Bs[128 * 64];

    const int t    = threadIdx.x;
    const int w    = t >> 6;
    const int lane = t & 63;
    const int l15  = lane & 15;
    const int quad = lane >> 4;
    const int wm   = w & 1;
    const int wn   = w >> 1;

    if (blockIdx.x < 1024) {
        const int bN = (blockIdx.x & 15) * 128;
        const int bM = (blockIdx.x >> 4) * 128;
        const int Kd = 768;

        const int srow = t >> 3;
        const int scol = ((t & 7) ^ ((t >> 4) & 7)) << 3;
        const unsigned short* ga = xkv + (size_t)(bM + srow) * Kd + scol;
        const unsigned short* gb = wkv + (size_t)(bN + srow) * Kd + scol;
        const int lbase = w * 512;

        const int xr = (l15 >> 1) & 7;
        int aoff[2][4], boff[2][4];
#pragma unroll
        for (int kk = 0; kk < 2; ++kk)
#pragma unroll
            for (int mt = 0; mt < 4; ++mt) {
                aoff[kk][mt] = (wm * 64 + mt * 16 + l15) * 64 + (((kk * 4 + quad) ^ xr) << 3);
                boff[kk][mt] = (wn * 64 + mt * 16 + l15) * 64 + (((kk * 4 + quad) ^ xr) << 3);
            }

        f32x4 acc[4][4];
#pragma unroll
        for (int mt = 0; mt < 4; ++mt)
#pragma unroll
            for (int nt = 0; nt < 4; ++nt)
#pragma unroll
                for (int r = 0; r < 4; ++r) acc[mt][nt][r] = 0.f;

        for (int k0 = 0; k0 < Kd; k0 += 64) {
            __syncthreads();
#pragma unroll
            for (int it = 0; it < 4; ++it) {
                load_lds16(ga + (size_t)it * 32 * Kd + k0, &As[lbase + it * 2048]);
                load_lds16(gb + (size_t)it * 32 * Kd + k0, &Bs[lbase + it * 2048]);
            }
            __syncthreads();

#pragma unroll
            for (int kk = 0; kk < 2; ++kk) {
                bf16x8 af[4], bf[4];
#pragma unroll
                for (int mt = 0; mt < 4; ++mt) af[mt] = *(const bf16x8*)&As[aoff[kk][mt]];
#pragma unroll
                for (int nt = 0; nt < 4; ++nt) bf[nt] = *(const bf16x8*)&Bs[boff[kk][nt]];
#pragma unroll
                for (int mt = 0; mt < 4; ++mt)
#pragma unroll
                    for (int nt = 0; nt < 4; ++nt)
                        acc[mt][nt] = __builtin_amdgcn_mfma_f32_16x16x32_bf16(af[mt], bf[nt], acc[mt][nt], 0, 0, 0);
            }
        }

        const int rbase = bM + wm * 64;
        const int b  = rbase >> 12;
        const int h  = (rbase & 4095) >> 8;
        if (bN < 1024) {
            const int G = (bN + wn * 64) >> 6;
            unsigned short* kp = Kn + (size_t)(b * 16 + h) * 262144 + (size_t)G * 256 * 64 + l15;
#pragma unroll
            for (int mt = 0; mt < 4; ++mt)
#pragma unroll
                for (int r = 0; r < 4; ++r) {
                    int u = (rbase & 255) + mt * 16 + quad * 4 + r;
                    unsigned short* cp = kp + (size_t)u * 64;
#pragma unroll
                    for (int nt = 0; nt < 4; ++nt) cp[nt * 16] = f2bf(acc[mt][nt][r]);
                }
        } else {
            const int Gv = (bN - 1024 + wn * 64) >> 6;
            unsigned short* vp = Vt + (size_t)(b * 16 + h) * 262144 + (size_t)Gv * 256;
#pragma unroll
            for (int nt = 0; nt < 4; ++nt) {
                int d = nt * 16 + l15;
#pragma unroll
                for (int mt = 0; mt < 4; ++mt) {
                    int u = (rbase & 255) + mt * 16 + quad * 4;
                    ushort4 pk;
                    pk.x = f2bf(acc[mt][nt][0]);
                    pk.y = f2bf(acc[mt][nt][1]);
                    pk.z = f2bf(acc[mt][nt][2]);
                    pk.w = f2bf(acc[mt][nt][3]);
                    *(ushort4*)(vp + (size_t)d * 4096 + u) = pk;
                }
            }
        }
    } else {
        const int id = blockIdx.x - 1024;           // 0..511
        const int bN = (id & 15) * 64;
        const int bM = (id >> 4) * 64;
        const int Kd = 1024, N = 1024;

        const int srow = t >> 3;
        const int scol = ((t & 7) ^ ((t >> 3) & 7)) << 3;
        const unsigned short* ga = xq + (size_t)(bM + srow) * Kd + scol;
        const unsigned short* gb = wq + (size_t)(bN + srow) * Kd + scol;
        const int lbase = w * 512;

        int aoff[2][2], boff[2][2];
#pragma unroll
        for (int kk = 0; kk < 2; ++kk)
#pragma unroll
            for (int mt = 0; mt < 2; ++mt) {
                aoff[kk][mt] = (wm * 32 + mt * 16 + l15) * 64 + (((kk * 4 + quad) ^ (l15 & 7)) << 3);
                boff[kk][mt] = (wn * 32 + mt * 16 + l15) * 64 + (((kk * 4 + quad) ^ (l15 & 7)) << 3);
            }

        f32x4 acc[2][2];
#pragma unroll
        for (int mt = 0; mt < 2; ++mt)
#pragma unroll
            for (int nt = 0; nt < 2; ++nt)
#pragma unroll
                for (int r = 0; r < 4; ++r) acc[mt][nt][r] = 0.f;

        for (int k0 = 0; k0 < Kd; k0 += 64) {
            __syncthreads();
#pragma unroll
            for (int it = 0; it < 2; ++it) {
                load_lds16(ga + (size_t)it * 32 * Kd + k0, &As[lbase + it * 2048]);
                load_lds16(gb + (size_t)it * 32 * Kd + k0, &Bs[lbase + it * 2048]);
            }
            __syncthreads();

#pragma unroll
            for (int kk = 0; kk < 2; ++kk) {
                bf16x8 af[2], bf[2];
#pragma unroll
                for (int mt = 0; mt < 2; ++mt) af[mt] = *(const bf16x8*)&As[aoff[kk][mt]];
#pragma unroll
                for (int nt = 0; nt < 2; ++nt) bf[nt] = *(const bf16x8*)&Bs[boff[kk][nt]];
#pragma unroll
                for (int mt = 0; mt < 2; ++mt)
#pragma unroll
                    for (int nt = 0; nt < 2; ++nt)
                        acc[mt][nt] = __builtin_amdgcn_mfma_f32_16x16x32_bf16(af[mt], bf[nt], acc[mt][nt], 0, 0, 0);
            }
        }

#pragma unroll
        for (int mt = 0; mt < 2; ++mt)
#pragma unroll
            for (int r = 0; r < 4; ++r) {
                int row = bM + wm * 32 + mt * 16 + quad * 4 + r;
                int col = bN + wn * 32 + l15;
                unsigned short* cp = Qout + (size_t)row * N + col;
#pragma unroll
                for (int nt = 0; nt < 2; ++nt) cp[nt * 16] = f2bf(acc[mt][nt][r]);
            }
    }
}

// ---------------------------------------------------------------------------
// 64x64-tile bf16 MFMA GEMM (Wo projection). (r13 verbatim)
// ---------------------------------------------------------------------------
template <bool OUTF32>
__global__ __launch_bounds__(THREADS)
void gemm_bf16_nt64(const unsigned short* __restrict__ A, const unsigned short* __restrict__ W,
                    void* __restrict__ Cout, int M, int N, int Kd) {
    __shared__ __align__(16) unsigned short As[64 * 64];
    __shared__ __align__(16) unsigned short Bs[64 * 64];

    const int t    = threadIdx.x;
    const int w    = t >> 6;
    const int lane = t & 63;
    const int l15  = lane & 15;
    const int quad = lane >> 4;
    const int wm   = w & 1;
    const int wn   = w >> 1;
    const int bM = blockIdx.y * 64;
    const int bN = blockIdx.x * 64;

    const int srow = t >> 3;
    const int scol = ((t & 7) ^ ((t >> 3) & 7)) << 3;
    const unsigned short* ga = A + (size_t)(bM + srow) * Kd + scol;
    const unsigned short* gb = W + (size_t)(bN + srow) * Kd + scol;
    const int lbase = w * 512;

    int aoff[2][2], boff[2][2];
#pragma unroll
    for (int kk = 0; kk < 2; ++kk)
#pragma unroll
        for (int mt = 0; mt < 2; ++mt) {
            aoff[kk][mt] = (wm * 32 + mt * 16 + l15) * 64 + (((kk * 4 + quad) ^ (l15 & 7)) << 3);
            boff[kk][mt] = (wn * 32 + mt * 16 + l15) * 64 + (((kk * 4 + quad) ^ (l15 & 7)) << 3);
        }

    f32x4 acc[2][2];
#pragma unroll
    for (int mt = 0; mt < 2; ++mt)
#pragma unroll
        for (int nt = 0; nt < 2; ++nt)
#pragma unroll
            for (int r = 0; r < 4; ++r) acc[mt][nt][r] = 0.f;

    for (int k0 = 0; k0 < Kd; k0 += 64) {
        __syncthreads();
#pragma unroll
        for (int it = 0; it < 2; ++it) {
            load_lds16(ga + (size_t)it * 32 * Kd + k0, &As[lbase + it * 2048]);
            load_lds16(gb + (size_t)it * 32 * Kd + k0, &Bs[lbase + it * 2048]);
        }
        __syncthreads();

#pragma unroll
        for (int kk = 0; kk < 2; ++kk) {
            bf16x8 af[2], bf[2];
#pragma unroll
            for (int mt = 0; mt < 2; ++mt) af[mt] = *(const bf16x8*)&As[aoff[kk][mt]];
#pragma unroll
            for (int nt = 0; nt < 2; ++nt) bf[nt] = *(const bf16x8*)&Bs[boff[kk][nt]];
#pragma unroll
            for (int mt = 0; mt < 2; ++mt)
#pragma unroll
                for (int nt = 0; nt < 2; ++nt)
                    acc[mt][nt] = __builtin_amdgcn_mfma_f32_16x16x32_bf16(af[mt], bf[nt], acc[mt][nt], 0, 0, 0);
        }
    }

#pragma unroll
    for (int mt = 0; mt < 2; ++mt)
#pragma unroll
        for (int r = 0; r < 4; ++r) {
            int row = bM + wm * 32 + mt * 16 + quad * 4 + r;
            int col = bN + wn * 32 + l15;
            if (OUTF32) {
                float* cp = (float*)Cout + (size_t)row * N + col;
#pragma unroll
                for (int nt = 0; nt < 2; ++nt) cp[nt * 16] = acc[mt][nt][r];
            } else {
                unsigned short* cp = (unsigned short*)Cout + (size_t)row * N + col;
#pragma unroll
                for (int nt = 0; nt < 2; ++nt) cp[nt * 16] = f2bf(acc[mt][nt][r]);
            }
        }
}

// ---------------------------------------------------------------------------
// Flash attention v9: barrier-free (r15) + PER-WAVE SOFTWARE PIPELINE.
// Exploits mid-iteration region death (no extra LDS):
//  - K-slice dead once the 4 K-frags are in regs -> prefetch K(kc+1) there,
//    hidden behind the S-phase (16 MFMA + 32 exps).
//  - V-slice dead once V-frags read -> prefetch V(kc+1) there, hidden behind
//    PV MFMAs + next iter's S-phase.
//  Steady state: 8 loads always in flight; waits are vmcnt(4), never 0
//  (the hipBLASLt/AITER pattern the 2-barrier structure couldn't express).
//  Prefetch index wraps (kc+1)&31 -> always in-bounds; the epilogue's first
//  __syncthreads drains the queue before the OS overlay reuses Ks/Vs.
// ---------------------------------------------------------------------------
__global__ __launch_bounds__(THREADS, 2)
void attn_mfma9(const unsigned short* __restrict__ Q, const unsigned short* __restrict__ K,
                const unsigned short* __restrict__ Vt, unsigned short* __restrict__ AO) {
    extern __shared__ __align__(16) unsigned short sm[];
    unsigned short* Ks = sm;              // [128kv][64d] row-swizzled, 8192 shorts
    unsigned short* Vs = sm + 8192;       // quarter-major [w][64d][4x16B], 8192 shorts
    unsigned short* Ps = sm + 16384;      // 4 waves x [64q][40], 10240 shorts
    float* OS = (float*)sm;               // epilogue: 3 x [64d][68q] f32
    float* Lw = (float*)(sm + 26624);     // 256 f32

    const int bid  = blockIdx.x;          // 0..511
    const int slot = bid >> 3;
    const int qq   = slot & 15;
    const int hh   = (bid & 7) + 8 * (slot >> 4);
    const int q0 = qq * 64;
    const int h  = hh & 15;
    const int b  = hh >> 4;

    const int t    = threadIdx.x;
    const int w    = t >> 6;              // kv-quarter owner
    const int lane = t & 63;
    const int l15  = lane & 15;
    const int quad = lane >> 4;

    const unsigned short* Qh = Q + (size_t)b * 1048576 + (size_t)h * 65536 + (size_t)q0 * 64;
    const unsigned short* Kh = K + (size_t)b * 4194304 + (size_t)h * 262144;
    const unsigned short* Vh = Vt + (size_t)(b * 16 + h) * 262144;

    bf16x8 Qb[4][2];
#pragma unroll
    for (int qt = 0; qt < 4; ++qt)
#pragma unroll
        for (int kk = 0; kk < 2; ++kk)
            Qb[qt][kk] = *(const bf16x8*)(Qh + (size_t)(qt * 16 + l15) * 64 + kk * 32 + quad * 8);

    // wave-private staging pointers (r15 layout)
    const unsigned short* gKw = Kh + (size_t)(w * 32 + (lane >> 3)) * 64
                                   + (((lane & 7) ^ ((lane >> 3) & 7)) << 3);
    const unsigned short* gVw = Vh + (size_t)(lane >> 2) * 4096 + w * 32
                                   + (((lane & 3) ^ ((lane >> 2) & 3)) << 3);
    const int ldsK = w * 2048;            // + it*512 (shorts)
    const int ldsV = w * 2048;            // + it*512 (shorts), within Vs

    int koff[2][2];
#pragma unroll
    for (int kvt = 0; kvt < 2; ++kvt)
#pragma unroll
        for (int kk = 0; kk < 2; ++kk)
            koff[kvt][kk] = (w * 32 + kvt * 16 + l15) * 64 + (((kk * 4 + quad) ^ (l15 & 7)) << 3);
    int voff[4];
#pragma unroll
    for (int dt = 0; dt < 4; ++dt)
        voff[dt] = w * 2048 + (dt * 16 + l15) * 32 + ((quad ^ (l15 & 3)) << 3);

    const int pw  = w * 2560;
    const int pq  = pw + l15 * 40;

    f32x4 Oacc[4][4];
#pragma unroll
    for (int qt = 0; qt < 4; ++qt)
#pragma unroll
        for (int dt = 0; dt < 4; ++dt)
#pragma unroll
            for (int r = 0; r < 4; ++r) Oacc[qt][dt][r] = 0.f;
    float lsum[4] = {0.f, 0.f, 0.f, 0.f};

    const float scale = 1.0f / 64.0f;

    // ---- prologue: stage chunk 0 (8 loads in flight = steady state) ----
#pragma unroll
    for (int it = 0; it < 4; ++it)
        load_lds16(gKw + it * 512, &Ks[ldsK + it * 512]);
#pragma unroll
    for (int it = 0; it < 4; ++it)
        load_lds16(gVw + (size_t)it * 65536, &Vs[ldsV + it * 512]);

    for (int kc = 0; kc < 32; ++kc) {
        const int kn = (kc + 1) & 31;    // wrap keeps prefetch in-bounds

        asm volatile("s_waitcnt vmcnt(4)" ::: "memory");   // K(kc) landed; V(kc) in flight

        // read ALL K frags, retire, then prefetch K(kn) into the dead K slice
        bf16x8 ka0 = *(const bf16x8*)&Ks[koff[0][0]];
        bf16x8 kb0 = *(const bf16x8*)&Ks[koff[0][1]];
        bf16x8 ka1 = *(const bf16x8*)&Ks[koff[1][0]];
        bf16x8 kb1 = *(const bf16x8*)&Ks[koff[1][1]];
        asm volatile("s_waitcnt lgkmcnt(0)" ::: "memory"); // K frags in regs
#pragma unroll
        for (int it = 0; it < 4; ++it)
            load_lds16(gKw + (size_t)kn * 8192 + it * 512, &Ks[ldsK + it * 512]);

        // ---- S-phase: S^T tiles, __expf, b64 P store (hides V + K-pref) ----
#pragma unroll
        for (int qt = 0; qt < 4; ++qt) {
            f32x4 S0 = {0.f, 0.f, 0.f, 0.f};
            S0 = __builtin_amdgcn_mfma_f32_16x16x32_bf16(ka0, Qb[qt][0], S0, 0, 0, 0);
            S0 = __builtin_amdgcn_mfma_f32_16x16x32_bf16(kb0, Qb[qt][1], S0, 0, 0, 0);
            f32x4 S1 = {0.f, 0.f, 0.f, 0.f};
            S1 = __builtin_amdgcn_mfma_f32_16x16x32_bf16(ka1, Qb[qt][0], S1, 0, 0, 0);
            S1 = __builtin_amdgcn_mfma_f32_16x16x32_bf16(kb1, Qb[qt][1], S1, 0, 0, 0);
            float p0 = __expf(S0[0] * scale);
            float p1 = __expf(S0[1] * scale);
            float p2 = __expf(S0[2] * scale);
            float p3 = __expf(S0[3] * scale);
            float p4 = __expf(S1[0] * scale);
            float p5 = __expf(S1[1] * scale);
            float p6 = __expf(S1[2] * scale);
            float p7 = __expf(S1[3] * scale);
            lsum[qt] += ((p0 + p1) + (p2 + p3)) + ((p4 + p5) + (p6 + p7));
            ushort4 pk4a, pk4b;
            pk4a.x = f2bf(p0); pk4a.y = f2bf(p1); pk4a.z = f2bf(p2); pk4a.w = f2bf(p3);
            pk4b.x = f2bf(p4); pk4b.y = f2bf(p5); pk4b.z = f2bf(p6); pk4b.w = f2bf(p7);
            *(ushort4*)&Ps[pq + qt * 640 + quad * 4]      = pk4a;
            *(ushort4*)&Ps[pq + qt * 640 + 16 + quad * 4] = pk4b;
        }

        asm volatile("s_waitcnt vmcnt(4)" ::: "memory");   // V(kc) landed; K(kn) in flight
        asm volatile("s_waitcnt lgkmcnt(0)" ::: "memory"); // P stores visible

        // read V + P frags, retire, then prefetch V(kn) into the dead V slice
        bf16x8 Vf[4], Pa[4];
#pragma unroll
        for (int dt = 0; dt < 4; ++dt) Vf[dt] = *(const bf16x8*)&Vs[voff[dt]];
#pragma unroll
        for (int qt = 0; qt < 4; ++qt) Pa[qt] = *(const bf16x8*)&Ps[pq + qt * 640 + quad * 8];
        asm volatile("s_waitcnt lgkmcnt(0)" ::: "memory"); // V/P frags in regs
#pragma unroll
        for (int it = 0; it < 4; ++it)
            load_lds16(gVw + (size_t)kn * 128 + (size_t)it * 65536, &Vs[ldsV + it * 512]);

        // ---- O += P @ V over this wave's 32 kv ----
#pragma unroll
        for (int qt = 0; qt < 4; ++qt)
#pragma unroll
            for (int dt = 0; dt < 4; ++dt)
                Oacc[qt][dt] = __builtin_amdgcn_mfma_f32_16x16x32_bf16(Pa[qt], Vf[dt], Oacc[qt][dt], 0, 0, 0);
    }

    // ---- epilogue (r15 verbatim; first barrier drains the wrap prefetch) ----
#pragma unroll
    for (int qt = 0; qt < 4; ++qt) {
        float v = lsum[qt];
        v += __shfl_xor(v, 16);
        v += __shfl_xor(v, 32);
        lsum[qt] = v;
    }
    __syncthreads();   // (1) all waves done with Ks/Vs/Ps; DMA queue drained
    if (lane < 16) {
#pragma unroll
        for (int qt = 0; qt < 4; ++qt)
            Lw[w * 64 + qt * 16 + lane] = lsum[qt];
    }
    if (w > 0) {
        float* myOS = OS + (w - 1) * 4352;
#pragma unroll
        for (int qt = 0; qt < 4; ++qt)
#pragma unroll
            for (int dt = 0; dt < 4; ++dt)
                *(f32x4*)&myOS[(dt * 16 + l15) * 68 + qt * 16 + quad * 4] = Oacc[qt][dt];
    }
    __syncthreads();   // (2) partials + Lw visible
    if (w == 0) {
#pragma unroll
        for (int qt = 0; qt < 4; ++qt) {
            f32x4 lv = *(const f32x4*)&Lw[qt * 16 + quad * 4];
            lv += *(const f32x4*)&Lw[64 + qt * 16 + quad * 4];
            lv += *(const f32x4*)&Lw[128 + qt * 16 + quad * 4];
            lv += *(const f32x4*)&Lw[192 + qt * 16 + quad * 4];
            f32x4 inv;
#pragma unroll
            for (int r = 0; r < 4; ++r) inv[r] = 1.0f / lv[r];
#pragma unroll
            for (int dt = 0; dt < 4; ++dt) {
                f32x4 o = Oacc[qt][dt];
                int os = (dt * 16 + l15) * 68 + qt * 16 + quad * 4;
                o += *(const f32x4*)&OS[os];
                o += *(const f32x4*)&OS[4352 + os];
                o += *(const f32x4*)&OS[8704 + os];
#pragma unroll
                for (int r = 0; r < 4; ++r) {
                    int q = qt * 16 + quad * 4 + r;
                    AO[(size_t)b * 1048576 + (size_t)(q0 + q) * 1024 + (h << 6) + dt * 16 + l15]
                        = f2bf(o[r] * inv[r]);
                }
            }
        }
    }
}

// ---------------------------------------------------------------------------
extern "C" void kernel_launch(void* const* d_in, const int* in_sizes, int n_in,
                              void* d_out, int out_size, void* d_ws, size_t ws_size,
                              hipStream_t stream) {
    const float* x_q  = (const float*)d_in[0];  // (2,1024,1024)
    const float* x_kv = (const float*)d_in[1];  // (2,4096,768)
    const float* Wq   = (const float*)d_in[2];
    const float* Wk   = (const float*)d_in[3];
    const float* Wv   = (const float*)d_in[4];
    const float* Wo   = (const float*)d_in[5];
    float* out = (float*)d_out;

    unsigned short* base   = (unsigned short*)d_ws;
    unsigned short* xq_bf  = base;                  // 2097152
    unsigned short* xkv_bf = base + 2097152;        // 6291456
    unsigned short* wq_bf  = base + 8388608;        // 1048576
    unsigned short* wk_bf  = base + 9437184;        //  786432  \ contiguous
    unsigned short* wv_bf  = base + 10223616;       //  786432  / [2048][768]
    unsigned short* wo_bf  = base + 11010048;       // 1048576
    unsigned short* Qw     = base + 12058624;       // 2097152
    unsigned short* Kw     = base + 14155776;       // 8388608
    unsigned short* AOb    = base + 22544384;       // 2097152
    unsigned short* Vtw    = base + 30932992;       // 8388608

    dim3 blk(THREADS);
    cast_inputs<<<dim3(11776), blk, 0, stream>>>(x_q, x_kv, Wq, Wk, Wv, Wo,
                                                 xq_bf, xkv_bf, wq_bf, wk_bf, wv_bf, wo_bf);
    gemm_proj<<<dim3(1536), blk, 0, stream>>>(xkv_bf, wk_bf, Kw, Vtw, xq_bf, wq_bf, Qw);
    attn_mfma9<<<dim3(512), blk, 54272, stream>>>(Qw, Kw, Vtw, AOb);
    gemm_bf16_nt64<true><<<dim3(16, 32), blk, 0, stream>>>(AOb, wo_bf, (void*)out, 2048, 1024, 1024);
}